// Round 8
// baseline (932.476 us; speedup 1.0000x reference)
//
#include <hip/hip_runtime.h>
#include <math.h>

#define NN 50000
#define NPAD 50048           // 391*128
#define IN_DIM 100
#define DD 128
#define HH 8
#define LL 3
#define GG 64
#define FFD 512
#define EE 800000

typedef __attribute__((ext_vector_type(8))) short bf8_t;   // 8 bf16 (4 VGPRs)
typedef __attribute__((ext_vector_type(4))) float f4_t;    // 4 fp32 acc

static __device__ __forceinline__ unsigned short f2bf(float f) {
    unsigned u = __builtin_bit_cast(unsigned, f);
    unsigned r = (u + 0x7FFFu + ((u >> 16) & 1u)) >> 16;
    return (unsigned short)r;
}
static __device__ __forceinline__ float bf2f(unsigned short b) {
    unsigned u = ((unsigned)b) << 16;
    return __builtin_bit_cast(float, u);
}

#define GLD16(gsrc, ldst) __builtin_amdgcn_global_load_lds( \
    (const __attribute__((address_space(1))) unsigned int*)(gsrc), \
    (__attribute__((address_space(3))) unsigned int*)(ldst), 16, 0, 0)

// ---------------------------------------------------------------------------
// Split-bf16 MFMA GEMM: C[n,M] = A[n,K] @ W[K,M].
// a_plain=0: Ac chunked hi/lo [n][nk][2][32], 3-mfma split.
// a_plain=1: Ac plain bf16 [n][nk*32], hi-only A, 2-mfma split.
// Bc: [M][nk][2][32] (transposed+split weights). 128x128 tile, 4 waves.
// ---------------------------------------------------------------------------
__global__ __launch_bounds__(256) void mfma_gemm(
    const unsigned short* __restrict__ Ac,
    const unsigned short* __restrict__ Bc,
    const float* __restrict__ bias,
    const float* __restrict__ resid,
    float* __restrict__ Cf,
    unsigned short* __restrict__ Chl,
    unsigned short* __restrict__ Cb,
    int n, int nk, int M, int do_relu, int a_plain)
{
    __shared__ unsigned short ldsA[128 * 64];
    __shared__ unsigned short ldsB[128 * 64];
    const int tid = threadIdx.x;
    const int lane = tid & 63;
    const int wid = tid >> 6;
    const int wr = (wid >> 1) * 64;
    const int wc = (wid & 1) * 64;
    const long brow = (long)blockIdx.x * 128;
    const long bcol = (long)blockIdx.y * 128;

    f4_t acc[4][4] = {};

    const int srow = tid >> 3;
    const int kbg = (((tid & 7) << 4) ^ ((srow & 7) << 4)) >> 1;
    const int fr = lane & 15;
    const int kq = (lane >> 4) << 4;
    const int kq4 = lane >> 4;

    for (int kc = 0; kc < nk; ++kc) {
        if (a_plain) {
            // A hi-only: 128 rows x 32 u16, slot^(row&3) pre-swizzle
#pragma unroll
            for (int i = 0; i < 2; ++i) {
                int lin = i * 256 + tid;
                int row = lin >> 2, sd = lin & 3;
                GLD16(Ac + (brow + row) * (size_t)(nk * 32) + kc * 32 + ((sd ^ (row & 3)) << 3),
                      &ldsA[(size_t)lin * 8]);
            }
        } else {
#pragma unroll
            for (int i = 0; i < 4; ++i) {
                int row = i * 32 + srow;
                GLD16(Ac + ((brow + row) * (size_t)nk + kc) * 64 + kbg,
                      &ldsA[((size_t)i * 256 + tid) * 8]);
            }
        }
#pragma unroll
        for (int i = 0; i < 4; ++i) {
            int row = i * 32 + srow;
            GLD16(Bc + ((bcol + row) * (size_t)nk + kc) * 64 + kbg,
                  &ldsB[((size_t)i * 256 + tid) * 8]);
        }
        __syncthreads();

        bf8_t bh[4], bl[4];
#pragma unroll
        for (int nn = 0; nn < 4; ++nn) {
            int row = wc + nn * 16 + fr;
            int sw = (row & 7) << 4;
            bh[nn] = *(const bf8_t*)&ldsB[row * 64 + ((kq ^ sw) >> 1)];
            bl[nn] = *(const bf8_t*)&ldsB[row * 64 + (((kq + 64) ^ sw) >> 1)];
        }
        if (a_plain) {
            bf8_t ah[4];
#pragma unroll
            for (int m = 0; m < 4; ++m) {
                int row = wr + m * 16 + fr;
                ah[m] = *(const bf8_t*)&ldsA[row * 32 + ((kq4 ^ (row & 3)) << 3)];
            }
#pragma unroll
            for (int m = 0; m < 4; ++m)
#pragma unroll
                for (int nn = 0; nn < 4; ++nn) {
                    acc[m][nn] = __builtin_amdgcn_mfma_f32_16x16x32_bf16(ah[m], bh[nn], acc[m][nn], 0, 0, 0);
                    acc[m][nn] = __builtin_amdgcn_mfma_f32_16x16x32_bf16(ah[m], bl[nn], acc[m][nn], 0, 0, 0);
                }
        } else {
            bf8_t ah[4], al[4];
#pragma unroll
            for (int m = 0; m < 4; ++m) {
                int row = wr + m * 16 + fr;
                int sw = (row & 7) << 4;
                ah[m] = *(const bf8_t*)&ldsA[row * 64 + ((kq ^ sw) >> 1)];
                al[m] = *(const bf8_t*)&ldsA[row * 64 + (((kq + 64) ^ sw) >> 1)];
            }
#pragma unroll
            for (int m = 0; m < 4; ++m)
#pragma unroll
                for (int nn = 0; nn < 4; ++nn) {
                    acc[m][nn] = __builtin_amdgcn_mfma_f32_16x16x32_bf16(ah[m], bh[nn], acc[m][nn], 0, 0, 0);
                    acc[m][nn] = __builtin_amdgcn_mfma_f32_16x16x32_bf16(al[m], bh[nn], acc[m][nn], 0, 0, 0);
                    acc[m][nn] = __builtin_amdgcn_mfma_f32_16x16x32_bf16(ah[m], bl[nn], acc[m][nn], 0, 0, 0);
                }
        }
        __syncthreads();
    }

    const int efr = lane & 15, efq = lane >> 4;
#pragma unroll
    for (int m = 0; m < 4; ++m) {
#pragma unroll
        for (int i = 0; i < 4; ++i) {
            long row = brow + wr + m * 16 + efq * 4 + i;
            if (row >= n) continue;
#pragma unroll
            for (int nn = 0; nn < 4; ++nn) {
                int col = (int)bcol + wc + nn * 16 + efr;
                float v = acc[m][nn][i];
                if (bias) v += bias[col];
                if (do_relu) v = fmaxf(v, 0.f);
                if (resid) v += resid[row * M + col];
                if (Cf) Cf[row * M + col] = v;
                if (Cb) Cb[row * M + col] = f2bf(v);
                if (Chl) {
                    unsigned short hb = f2bf(v);
                    float lo = v - bf2f(hb);
                    size_t cb = (row * (size_t)(M >> 5) + (col >> 5)) * 64 + (col & 31);
                    Chl[cb] = hb;
                    Chl[cb + 32] = f2bf(lo);
                }
            }
        }
    }
}

// ---------------------------------------------------------------------------
// Fused FF v4: h = h + relu(h@W1 + b1)@W2 + b2, fc never leaves LDS.
// 64-row tiles. A (hi-only h) in REGISTERS (loaded once, direct global).
// 32 B-tiles (4c x {W1 k0..3, W2 k0..3}) pipelined through double-buffered
// ldsB with STAGE(t+1) issued before compute(t): ONE barrier per tile.
// LDS 48 KB -> 3 blocks/CU.
// ---------------------------------------------------------------------------
#define FF_STAGE(T, BUF) do {                                                   \
    const int c_ = (T) >> 3, ph_ = ((T) >> 2) & 1, j_ = (T) & 3;                \
    _Pragma("unroll")                                                           \
    for (int i_ = 0; i_ < 4; ++i_) {                                            \
        int row_ = i_ * 32 + srow;                                              \
        const unsigned short* srcp_ = (ph_ == 0)                                \
            ? W1T + (((size_t)c_ * 128 + row_) * 4 + j_) * 64 + kbg             \
            : W2T + ((size_t)row_ * 16 + (c_ * 4 + j_)) * 64 + kbg;             \
        GLD16(srcp_, &ldsB[BUF][((size_t)i_ * 256 + tid) * 8]);                 \
    }                                                                           \
} while (0)

__global__ __launch_bounds__(256, 3) void ff_fused(
    const unsigned short* __restrict__ hcin,   // [NPAD][4][2][32]
    const unsigned short* __restrict__ W1T,    // [512][4][2][32]
    const unsigned short* __restrict__ W2T,    // [128][16][2][32]
    const float* __restrict__ b1,              // [512]
    const float* __restrict__ b2,              // [128]
    float* __restrict__ h,                     // [NPAD][128] resid in/out
    unsigned short* __restrict__ hcout,        // [NPAD][4][2][32] or null
    int n)
{
    __shared__ unsigned short ldsB[2][128 * 64];  // 32 KB double buffer
    __shared__ unsigned short midb[64 * 128];     // 16 KB, bf16, swizzled

    const int tid = threadIdx.x;
    const int lane = tid & 63;
    const int wid = tid >> 6;
    const int wr = (wid >> 1) * 32;             // {0,32}
    const int wc = (wid & 1) * 64;              // {0,64}
    const long brow = (long)blockIdx.x * 64;

    const int srow = tid >> 3;
    const int kbg = (((tid & 7) << 4) ^ ((srow & 7) << 4)) >> 1;  // B pre-swizzle
    const int fr = lane & 15;
    const int kq = (lane >> 4) << 4;            // B k-group byte offset
    const int kq4 = lane >> 4;                  // A k-group index
    const int efr = lane & 15, efq = lane >> 4;

    // A fragments (hi of h) in registers: rows wr+m*16+fr, 4 k-chunks, 16B each
    bf8_t ahr[2][4];
#pragma unroll
    for (int m = 0; m < 2; ++m) {
        long arow = brow + wr + m * 16 + fr;
#pragma unroll
        for (int kc = 0; kc < 4; ++kc)
            ahr[m][kc] = *(const bf8_t*)&hcin[(arow * 4 + kc) * (size_t)64 + kq4 * 8];
    }

    FF_STAGE(0, 0);

    f4_t acc1[2][4];
    f4_t acc2[2][4];
#pragma unroll
    for (int m = 0; m < 2; ++m)
#pragma unroll
        for (int nn = 0; nn < 4; ++nn) {
            acc2[m][nn][0] = 0.f; acc2[m][nn][1] = 0.f;
            acc2[m][nn][2] = 0.f; acc2[m][nn][3] = 0.f;
        }

    __syncthreads();   // buf0 staged (syncthreads drains vmcnt)

#pragma unroll
    for (int t = 0; t < 32; ++t) {
        const int c = t >> 3, ph = (t >> 2) & 1, j = t & 3;
        const int cur = t & 1;
        if (t < 31) FF_STAGE(t + 1, cur ^ 1);

        if (ph == 0) {
            // ---- W1 tile: acc1 += ahr[.][j] @ W1[c][j] ----
            if (j == 0) {
#pragma unroll
                for (int m = 0; m < 2; ++m)
#pragma unroll
                    for (int nn = 0; nn < 4; ++nn) {
                        acc1[m][nn][0] = 0.f; acc1[m][nn][1] = 0.f;
                        acc1[m][nn][2] = 0.f; acc1[m][nn][3] = 0.f;
                    }
            }
            bf8_t bh[4], bl[4];
#pragma unroll
            for (int nn = 0; nn < 4; ++nn) {
                int rowb = wc + nn * 16 + fr;
                int sw = (rowb & 7) << 4;
                bh[nn] = *(const bf8_t*)&ldsB[cur][rowb * 64 + ((kq ^ sw) >> 1)];
                bl[nn] = *(const bf8_t*)&ldsB[cur][rowb * 64 + (((kq + 64) ^ sw) >> 1)];
            }
#pragma unroll
            for (int m = 0; m < 2; ++m)
#pragma unroll
                for (int nn = 0; nn < 4; ++nn) {
                    acc1[m][nn] = __builtin_amdgcn_mfma_f32_16x16x32_bf16(ahr[m][j], bh[nn], acc1[m][nn], 0, 0, 0);
                    acc1[m][nn] = __builtin_amdgcn_mfma_f32_16x16x32_bf16(ahr[m][j], bl[nn], acc1[m][nn], 0, 0, 0);
                }
            if (j == 3) {
                // epilogue 1: relu(+b1) -> midb [64][128] bf16, byte^((row&7)<<4)
#pragma unroll
                for (int m = 0; m < 2; ++m)
#pragma unroll
                    for (int i = 0; i < 4; ++i) {
                        int lrow = wr + m * 16 + efq * 4 + i;
#pragma unroll
                        for (int nn = 0; nn < 4; ++nn) {
                            int col = wc + nn * 16 + efr;
                            float v = fmaxf(acc1[m][nn][i] + b1[c * 128 + col], 0.f);
                            int e2 = (lrow << 7) + ((((col << 1) ^ ((lrow & 7) << 4))) >> 1);
                            midb[e2] = f2bf(v);
                        }
                    }
            }
        } else {
            // ---- W2 tile: acc2 += mid[., c*128+j*32..] @ W2[c*4+j] ----
            bf8_t am[2], bh2[4], bl2[4];
#pragma unroll
            for (int m = 0; m < 2; ++m) {
                int lrow = wr + m * 16 + fr;
                int kbyte = (j * 64 + kq) ^ ((lrow & 7) << 4);
                am[m] = *(const bf8_t*)&midb[(lrow << 7) + (kbyte >> 1)];
            }
#pragma unroll
            for (int nn = 0; nn < 4; ++nn) {
                int rowb = wc + nn * 16 + fr;
                int sw = (rowb & 7) << 4;
                bh2[nn] = *(const bf8_t*)&ldsB[cur][rowb * 64 + ((kq ^ sw) >> 1)];
                bl2[nn] = *(const bf8_t*)&ldsB[cur][rowb * 64 + (((kq + 64) ^ sw) >> 1)];
            }
#pragma unroll
            for (int m = 0; m < 2; ++m)
#pragma unroll
                for (int nn = 0; nn < 4; ++nn) {
                    acc2[m][nn] = __builtin_amdgcn_mfma_f32_16x16x32_bf16(am[m], bh2[nn], acc2[m][nn], 0, 0, 0);
                    acc2[m][nn] = __builtin_amdgcn_mfma_f32_16x16x32_bf16(am[m], bl2[nn], acc2[m][nn], 0, 0, 0);
                }
        }
        __syncthreads();
    }

    // epilogue 2: h += ff + b2 ; rewrite h fp32 (+ hc hi/lo unless last layer)
#pragma unroll
    for (int m = 0; m < 2; ++m)
#pragma unroll
        for (int i = 0; i < 4; ++i) {
            long row = brow + wr + m * 16 + efq * 4 + i;
            if (row >= n) continue;
#pragma unroll
            for (int nn = 0; nn < 4; ++nn) {
                int col = wc + nn * 16 + efr;
                float v = acc2[m][nn][i] + b2[col] + h[row * 128 + col];
                h[row * 128 + col] = v;
                if (hcout) {
                    unsigned short hb = f2bf(v);
                    size_t cb = (row * (size_t)4 + (col >> 5)) * 64 + (col & 31);
                    hcout[cb] = hb;
                    hcout[cb + 32] = f2bf(v - bf2f(hb));
                }
            }
        }
}

__global__ void cvt_x_kernel(const float* __restrict__ x, unsigned short* __restrict__ xc)
{
    int idx = blockIdx.x * 256 + threadIdx.x;
    if (idx >= NN * 128) return;
    int node = idx >> 7, col = idx & 127;
    float v = (col < IN_DIM) ? x[(size_t)node * IN_DIM + col] : 0.f;
    unsigned short hb = f2bf(v);
    float lo = v - bf2f(hb);
    size_t b = (size_t)node * 256 + (col >> 5) * 64 + (col & 31);
    xc[b] = hb;
    xc[b + 32] = f2bf(lo);
}

// 16 weight matrices: 1 emb + (Wqk, Wv, Wo, W1, W2) x 3 layers
struct WDesc { const float* W; unsigned short* Wt; int K, nkpad, M, base; };
struct WDescs { WDesc d[16]; int n; int total; };

__global__ void wcvt_all_kernel(WDescs ds)
{
    int idx = blockIdx.x * 256 + threadIdx.x;
    if (idx >= ds.total) return;
    int di = 0;
    while (di + 1 < ds.n && idx >= ds.d[di + 1].base) ++di;
    WDesc w = ds.d[di];
    int loc = idx - w.base;
    int m = loc % w.M;
    int kc = loc / w.M;
    size_t ob = ((size_t)m * w.nkpad + kc) * 64;
    for (int i = 0; i < 32; ++i) {
        int k = kc * 32 + i;
        float v = (k < w.K) ? w.W[(size_t)k * w.M + m] : 0.f;
        unsigned short hb = f2bf(v);
        w.Wt[ob + i] = hb;
        w.Wt[ob + 32 + i] = f2bf(v - bf2f(hb));
    }
}

__global__ void count_kernel(const int* __restrict__ dst, int* __restrict__ counts)
{
    int e = blockIdx.x * 256 + threadIdx.x;
    if (e < EE) atomicAdd(&counts[dst[e]], 1);
}

__global__ __launch_bounds__(1024) void scan1_kernel(
    const int* __restrict__ counts, int* __restrict__ offsets, int* __restrict__ bsums)
{
    __shared__ int buf[1024];
    int tid = threadIdx.x;
    int i = blockIdx.x * 1024 + tid;
    int v = (i < NN) ? counts[i] : 0;
    buf[tid] = v;
    __syncthreads();
    for (int off = 1; off < 1024; off <<= 1) {
        int t = (tid >= off) ? buf[tid - off] : 0;
        __syncthreads();
        buf[tid] += t;
        __syncthreads();
    }
    if (i < NN) offsets[i + 1] = buf[tid];
    if (tid == 1023) bsums[blockIdx.x] = buf[1023];
}

__global__ void scan2_kernel(int* __restrict__ bsums, int nb)
{
    __shared__ int buf[64];
    int tid = threadIdx.x;
    int v = (tid < nb) ? bsums[tid] : 0;
    buf[tid] = v;
    __syncthreads();
    for (int off = 1; off < 64; off <<= 1) {
        int t = (tid >= off) ? buf[tid - off] : 0;
        __syncthreads();
        buf[tid] += t;
        __syncthreads();
    }
    if (tid < nb) bsums[tid] = buf[tid] - v;   // exclusive
}

__global__ __launch_bounds__(1024) void scan3_kernel(
    int* __restrict__ offsets, const int* __restrict__ bsums)
{
    int i = blockIdx.x * 1024 + threadIdx.x;
    if (i < NN) offsets[i + 1] += bsums[blockIdx.x];
    if (i == 0) offsets[0] = 0;
}

__global__ void fill_kernel(const int* __restrict__ src, const int* __restrict__ dst,
                            const int* __restrict__ offsets, int* __restrict__ cursor,
                            int* __restrict__ csr_src)
{
    int e = blockIdx.x * 256 + threadIdx.x;
    if (e < EE) {
        int d = dst[e];
        int pos = atomicAdd(&cursor[d], 1);
        csr_src[offsets[d] + pos] = src[e];
    }
}

// ---------------------------------------------------------------------------
// Fused attention: one wave per dst node; 8 heads x 8 lanes (2 dims/lane).
// QKV plain bf16 [n][384] (q|k|v). Online softmax, 4-edge unrolled.
// Output: plain bf16 ac[n][128].
// ---------------------------------------------------------------------------
__global__ __launch_bounds__(256) void attn_kernel(
    const unsigned short* __restrict__ QKV,
    const int* __restrict__ offsets, const int* __restrict__ csr_src,
    unsigned short* __restrict__ ac)    // [n][128] plain bf16
{
    int wave = threadIdx.x >> 6;
    int lane = threadIdx.x & 63;
    int node = blockIdx.x * 4 + wave;
    if (node >= NN) return;
    int qoff = ((lane >> 3) << 4) + ((lane & 7) << 1);
    ushort2 k2 = *(const ushort2*)&QKV[(size_t)node * 384 + 128 + qoff];
    float kx = bf2f(k2.x), ky = bf2f(k2.y);
    float m = -INFINITY, s = 0.f, a0 = 0.f, a1 = 0.f;
    int e = offsets[node], end = offsets[node + 1];
    for (; e + 3 < end; e += 4) {
        int j0 = csr_src[e], j1 = csr_src[e + 1], j2 = csr_src[e + 2], j3 = csr_src[e + 3];
        ushort2 q0 = *(const ushort2*)&QKV[(size_t)j0 * 384 + qoff];
        ushort2 q1 = *(const ushort2*)&QKV[(size_t)j1 * 384 + qoff];
        ushort2 q2 = *(const ushort2*)&QKV[(size_t)j2 * 384 + qoff];
        ushort2 q3 = *(const ushort2*)&QKV[(size_t)j3 * 384 + qoff];
        ushort2 v0 = *(const ushort2*)&QKV[(size_t)j0 * 384 + 256 + qoff];
        ushort2 v1 = *(const ushort2*)&QKV[(size_t)j1 * 384 + 256 + qoff];
        ushort2 v2 = *(const ushort2*)&QKV[(size_t)j2 * 384 + 256 + qoff];
        ushort2 v3 = *(const ushort2*)&QKV[(size_t)j3 * 384 + 256 + qoff];
        float p0 = kx * bf2f(q0.x) + ky * bf2f(q0.y);
        float p1 = kx * bf2f(q1.x) + ky * bf2f(q1.y);
        float p2 = kx * bf2f(q2.x) + ky * bf2f(q2.y);
        float p3 = kx * bf2f(q3.x) + ky * bf2f(q3.y);
        p0 += __shfl_xor(p0, 1, 64); p0 += __shfl_xor(p0, 2, 64); p0 += __shfl_xor(p0, 4, 64);
        p1 += __shfl_xor(p1, 1, 64); p1 += __shfl_xor(p1, 2, 64); p1 += __shfl_xor(p1, 4, 64);
        p2 += __shfl_xor(p2, 1, 64); p2 += __shfl_xor(p2, 2, 64); p2 += __shfl_xor(p2, 4, 64);
        p3 += __shfl_xor(p3, 1, 64); p3 += __shfl_xor(p3, 2, 64); p3 += __shfl_xor(p3, 4, 64);
        float sc0 = p0 * 0.25f, sc1 = p1 * 0.25f, sc2 = p2 * 0.25f, sc3 = p3 * 0.25f;
        float mx = fmaxf(fmaxf(fmaxf(sc0, sc1), fmaxf(sc2, sc3)), m);
        float corr = __expf(m - mx);
        float w0 = __expf(sc0 - mx), w1 = __expf(sc1 - mx);
        float w2 = __expf(sc2 - mx), w3 = __expf(sc3 - mx);
        s  = s  * corr + (w0 + w1) + (w2 + w3);
        a0 = a0 * corr + w0 * bf2f(v0.x) + w1 * bf2f(v1.x) + w2 * bf2f(v2.x) + w3 * bf2f(v3.x);
        a1 = a1 * corr + w0 * bf2f(v0.y) + w1 * bf2f(v1.y) + w2 * bf2f(v2.y) + w3 * bf2f(v3.y);
        m = mx;
    }
    if (e + 1 < end) {
        int j0 = csr_src[e], j1 = csr_src[e + 1];
        ushort2 q0 = *(const ushort2*)&QKV[(size_t)j0 * 384 + qoff];
        ushort2 v0 = *(const ushort2*)&QKV[(size_t)j0 * 384 + 256 + qoff];
        ushort2 q1 = *(const ushort2*)&QKV[(size_t)j1 * 384 + qoff];
        ushort2 v1 = *(const ushort2*)&QKV[(size_t)j1 * 384 + 256 + qoff];
        float p0 = kx * bf2f(q0.x) + ky * bf2f(q0.y);
        float p1 = kx * bf2f(q1.x) + ky * bf2f(q1.y);
        p0 += __shfl_xor(p0, 1, 64); p0 += __shfl_xor(p0, 2, 64); p0 += __shfl_xor(p0, 4, 64);
        p1 += __shfl_xor(p1, 1, 64); p1 += __shfl_xor(p1, 2, 64); p1 += __shfl_xor(p1, 4, 64);
        float sc0 = p0 * 0.25f, sc1 = p1 * 0.25f;
        float mn = fmaxf(m, fmaxf(sc0, sc1));
        float corr = __expf(m - mn);
        float w0 = __expf(sc0 - mn), w1 = __expf(sc1 - mn);
        s  = s  * corr + w0 + w1;
        a0 = a0 * corr + w0 * bf2f(v0.x) + w1 * bf2f(v1.x);
        a1 = a1 * corr + w0 * bf2f(v0.y) + w1 * bf2f(v1.y);
        m = mn;
        e += 2;
    }
    if (e < end) {
        int j = csr_src[e];
        ushort2 qj = *(const ushort2*)&QKV[(size_t)j * 384 + qoff];
        ushort2 vj = *(const ushort2*)&QKV[(size_t)j * 384 + 256 + qoff];
        float p = kx * bf2f(qj.x) + ky * bf2f(qj.y);
        p += __shfl_xor(p, 1, 64); p += __shfl_xor(p, 2, 64); p += __shfl_xor(p, 4, 64);
        float score = p * 0.25f;
        float mn = fmaxf(m, score);
        float corr = __expf(m - mn);
        float w = __expf(score - mn);
        s  = s  * corr + w;
        a0 = a0 * corr + w * bf2f(vj.x);
        a1 = a1 * corr + w * bf2f(vj.y);
        m = mn;
    }
    float inv = 1.f / (s + 1e-16f);
    ushort2 o;
    o.x = f2bf(a0 * inv);
    o.y = f2bf(a1 * inv);
    *(ushort2*)&ac[(size_t)node * 128 + qoff] = o;
}

// ---------------------------------------------------------------------------
// Mean pool per graph: 256 rows/block striped 8 ways, float4 cols
// ---------------------------------------------------------------------------
__global__ __launch_bounds__(256) void pool_kernel(
    const float* __restrict__ h, const int* __restrict__ batch,
    float* __restrict__ sums, int* __restrict__ cnts)
{
    int tid = threadIdx.x;
    int c4 = tid & 31;
    int rs = tid >> 5;
    int start = blockIdx.x * 256;
    int r0 = start + rs;
    if (r0 >= NN) return;
    int lim = min(start + 256, NN);
    float4 acc = make_float4(0.f, 0.f, 0.f, 0.f);
    int cnt = 0;
    int cur = batch[r0];
    for (int r = r0; r < lim; r += 8) {
        int g = batch[r];
        if (g != cur) {
            atomicAdd(&sums[cur * DD + c4 * 4 + 0], acc.x);
            atomicAdd(&sums[cur * DD + c4 * 4 + 1], acc.y);
            atomicAdd(&sums[cur * DD + c4 * 4 + 2], acc.z);
            atomicAdd(&sums[cur * DD + c4 * 4 + 3], acc.w);
            if (c4 == 0) atomicAdd(&cnts[cur], cnt);
            acc = make_float4(0.f, 0.f, 0.f, 0.f);
            cnt = 0; cur = g;
        }
        float4 v = *(const float4*)&h[(size_t)r * DD + c4 * 4];
        acc.x += v.x; acc.y += v.y; acc.z += v.z; acc.w += v.w;
        ++cnt;
    }
    atomicAdd(&sums[cur * DD + c4 * 4 + 0], acc.x);
    atomicAdd(&sums[cur * DD + c4 * 4 + 1], acc.y);
    atomicAdd(&sums[cur * DD + c4 * 4 + 2], acc.z);
    atomicAdd(&sums[cur * DD + c4 * 4 + 3], acc.w);
    if (c4 == 0) atomicAdd(&cnts[cur], cnt);
}

__global__ void finalize_kernel(const float* __restrict__ sums, const int* __restrict__ cnts,
                                float* __restrict__ out)
{
    int g = blockIdx.x, c = threadIdx.x;
    out[g * DD + c] = sums[g * DD + c] / fmaxf((float)cnts[g], 1.f);
}

extern "C" void kernel_launch(void* const* d_in, const int* in_sizes, int n_in,
                              void* d_out, int out_size, void* d_ws, size_t ws_size,
                              hipStream_t stream)
{
    const float* x     = (const float*)d_in[0];
    const float* emb_W = (const float*)d_in[1];
    const float* Wqk   = (const float*)d_in[2];
    const float* Wv    = (const float*)d_in[3];
    const float* Wo    = (const float*)d_in[4];
    const float* bo    = (const float*)d_in[5];
    const float* W1    = (const float*)d_in[6];
    const float* b1    = (const float*)d_in[7];
    const float* W2    = (const float*)d_in[8];
    const float* b2    = (const float*)d_in[9];
    const int* eidx    = (const int*)d_in[10];
    const int* batch   = (const int*)d_in[11];
    float* out = (float*)d_out;

    char* base = (char*)d_ws;
    size_t off = 0;
    auto alloc = [&](size_t bytes) { char* p = base + off; off = (off + bytes + 255) & ~(size_t)255; return p; };

    float*          h    = (float*)alloc((size_t)NPAD * DD * 4);
    unsigned short* hc   = (unsigned short*)alloc((size_t)NPAD * 2 * DD * 2);
    char*           regB = alloc((size_t)NPAD * 384 * 2 + (size_t)NPAD * 128 * 2 + 256);
    unsigned short* xc   = (unsigned short*)regB;                                // phase 0
    unsigned short* QKVb = (unsigned short*)regB;                                // per-layer ph 1
    unsigned short* acp  = (unsigned short*)(regB + (size_t)NPAD * 384 * 2);     // [NPAD][128] plain

    unsigned short* WqkvT = (unsigned short*)alloc((size_t)LL * 384 * 256 * 2);
    unsigned short* WoT   = (unsigned short*)alloc((size_t)LL * 128 * 256 * 2);
    unsigned short* W1T   = (unsigned short*)alloc((size_t)LL * 512 * 256 * 2);
    unsigned short* W2T   = (unsigned short*)alloc((size_t)LL * 128 * 1024 * 2);
    unsigned short* embT  = (unsigned short*)alloc((size_t)128 * 256 * 2);

    int* counts  = (int*)alloc((NN + 1) * 4);
    int* offsets = (int*)alloc((NN + 1) * 4);
    int* cursor  = (int*)alloc(NN * 4);
    int* bsums   = (int*)alloc(64 * 4);
    int* csr_src = (int*)alloc((size_t)EE * 4);
    float* sums  = (float*)alloc(GG * DD * 4 + GG * 4);
    int* cnts    = (int*)(sums + GG * DD);

    const int* src = eidx;
    const int* dst = eidx + EE;

    hipMemsetAsync(counts, 0, (NN + 1) * sizeof(int), stream);
    hipMemsetAsync(cursor, 0, NN * sizeof(int), stream);
    hipMemsetAsync(sums, 0, GG * DD * sizeof(float) + GG * sizeof(int), stream);

    const int NB1 = (NN + 1023) / 1024;   // 49
    count_kernel<<<dim3((EE + 255) / 256), dim3(256), 0, stream>>>(dst, counts);
    scan1_kernel<<<dim3(NB1), dim3(1024), 0, stream>>>(counts, offsets, bsums);
    scan2_kernel<<<dim3(1), dim3(64), 0, stream>>>(bsums, NB1);
    scan3_kernel<<<dim3(NB1), dim3(1024), 0, stream>>>(offsets, bsums);
    fill_kernel<<<dim3((EE + 255) / 256), dim3(256), 0, stream>>>(src, dst, offsets, cursor, csr_src);

    WDescs ds;
    int b = 0, di = 0;
    auto addw = [&](const float* W, unsigned short* Wt, int K, int nkpad, int M) {
        ds.d[di].W = W; ds.d[di].Wt = Wt; ds.d[di].K = K;
        ds.d[di].nkpad = nkpad; ds.d[di].M = M; ds.d[di].base = b;
        b += M * nkpad; ++di;
    };
    addw(emb_W, embT, IN_DIM, 4, DD);
    for (int l = 0; l < LL; ++l) {
        addw(Wqk + (size_t)l * DD * 256, WqkvT + (size_t)l * 384 * 256, DD, 4, 256);
        addw(Wv  + (size_t)l * DD * DD,  WqkvT + (size_t)l * 384 * 256 + 256 * 256, DD, 4, 128);
        addw(Wo  + (size_t)l * DD * DD,  WoT + (size_t)l * 128 * 256, DD, 4, 128);
        addw(W1  + (size_t)l * DD * FFD, W1T + (size_t)l * 512 * 256, DD, 4, 512);
        addw(W2  + (size_t)l * FFD * DD, W2T + (size_t)l * 128 * 1024, FFD, 16, 128);
    }
    ds.n = di; ds.total = b;   // di == 16
    wcvt_all_kernel<<<dim3((b + 255) / 256), dim3(256), 0, stream>>>(ds);

    cvt_x_kernel<<<dim3((NN * 128 + 255) / 256), dim3(256), 0, stream>>>(x, xc);

    dim3 blk(256);
    const int gx = (NN + 127) / 128;   // 391
    const int gx2 = (NN + 63) / 64;    // 782

    // emb: h = x @ emb_W  (fp32 h + hi/lo hc)
    mfma_gemm<<<dim3(gx, 1), blk, 0, stream>>>(
        xc, embT, nullptr, nullptr, h, hc, nullptr, NN, 4, DD, 0, 0);

    for (int l = 0; l < LL; ++l) {
        // QKV = h @ [Wqk|Wv] -> plain bf16 [n][384]
        mfma_gemm<<<dim3(gx, 3), blk, 0, stream>>>(
            hc, WqkvT + (size_t)l * 384 * 256, nullptr, nullptr,
            nullptr, nullptr, QKVb, NN, 4, 384, 0, 0);
        attn_kernel<<<dim3(NN / 4), blk, 0, stream>>>(QKVb, offsets, csr_src, acp);
        // h = h + ac @ Wo + bo  (plain-A path; fp32 h + hi/lo hc)
        mfma_gemm<<<dim3(gx, 1), blk, 0, stream>>>(
            acp, WoT + (size_t)l * 128 * 256, bo + (size_t)l * DD, h,
            h, hc, nullptr, NN, 4, DD, 0, 1);
        // h = h + relu(h@W1+b1)@W2 + b2  (pipelined fused FF)
        ff_fused<<<dim3(gx2), blk, 0, stream>>>(
            hc, W1T + (size_t)l * 512 * 256, W2T + (size_t)l * 128 * 1024,
            b1 + (size_t)l * FFD, b2 + (size_t)l * DD, h,
            (l == LL - 1) ? nullptr : hc, NN);
    }

    pool_kernel<<<dim3((NN + 255) / 256), blk, 0, stream>>>(h, batch, sums, cnts);
    finalize_kernel<<<dim3(GG), dim3(128), 0, stream>>>(sums, cnts, out);
}

// Round 9
// 740.204 us; speedup vs baseline: 1.2598x; 1.2598x over previous
//
#include <hip/hip_runtime.h>
#include <math.h>

#define NN 50000
#define NPAD 50048           // 391*128
#define IN_DIM 100
#define DD 128
#define HH 8
#define LL 3
#define GG 64
#define FFD 512
#define EE 800000

typedef __attribute__((ext_vector_type(8))) short bf8_t;   // 8 bf16 (4 VGPRs)
typedef __attribute__((ext_vector_type(4))) float f4_t;    // 4 fp32 acc

static __device__ __forceinline__ unsigned short f2bf(float f) {
    unsigned u = __builtin_bit_cast(unsigned, f);
    unsigned r = (u + 0x7FFFu + ((u >> 16) & 1u)) >> 16;
    return (unsigned short)r;
}
static __device__ __forceinline__ float bf2f(unsigned short b) {
    unsigned u = ((unsigned)b) << 16;
    return __builtin_bit_cast(float, u);
}

#define GLD16(gsrc, ldst) __builtin_amdgcn_global_load_lds( \
    (const __attribute__((address_space(1))) unsigned int*)(gsrc), \
    (__attribute__((address_space(3))) unsigned int*)(ldst), 16, 0, 0)

// ---------------------------------------------------------------------------
// Split-bf16 MFMA GEMM: C[n,M] = A[n,K] @ W[K,M].
// Ac chunked hi/lo [n][nk][2][32], 3-mfma split (Markidis).
// Bc: [M][nk][2][32] (transposed+split weights). 128x128 tile, 4 waves.
// ---------------------------------------------------------------------------
__global__ __launch_bounds__(256) void mfma_gemm(
    const unsigned short* __restrict__ Ac,
    const unsigned short* __restrict__ Bc,
    const float* __restrict__ bias,
    const float* __restrict__ resid,
    float* __restrict__ Cf,
    unsigned short* __restrict__ Chl,
    unsigned short* __restrict__ Cb,
    int n, int nk, int M, int do_relu)
{
    __shared__ unsigned short ldsA[128 * 64];
    __shared__ unsigned short ldsB[128 * 64];
    const int tid = threadIdx.x;
    const int lane = tid & 63;
    const int wid = tid >> 6;
    const int wr = (wid >> 1) * 64;
    const int wc = (wid & 1) * 64;
    const long brow = (long)blockIdx.x * 128;
    const long bcol = (long)blockIdx.y * 128;

    f4_t acc[4][4] = {};

    const int srow = tid >> 3;
    const int kbg = (((tid & 7) << 4) ^ ((srow & 7) << 4)) >> 1;
    const int fr = lane & 15;
    const int kq = (lane >> 4) << 4;

    for (int kc = 0; kc < nk; ++kc) {
#pragma unroll
        for (int i = 0; i < 4; ++i) {
            int row = i * 32 + srow;
            GLD16(Ac + ((brow + row) * (size_t)nk + kc) * 64 + kbg,
                  &ldsA[((size_t)i * 256 + tid) * 8]);
            GLD16(Bc + ((bcol + row) * (size_t)nk + kc) * 64 + kbg,
                  &ldsB[((size_t)i * 256 + tid) * 8]);
        }
        __syncthreads();

        bf8_t ah[4], al[4], bh[4], bl[4];
#pragma unroll
        for (int m = 0; m < 4; ++m) {
            int row = wr + m * 16 + fr;
            int sw = (row & 7) << 4;
            ah[m] = *(const bf8_t*)&ldsA[row * 64 + ((kq ^ sw) >> 1)];
            al[m] = *(const bf8_t*)&ldsA[row * 64 + (((kq + 64) ^ sw) >> 1)];
        }
#pragma unroll
        for (int nn = 0; nn < 4; ++nn) {
            int row = wc + nn * 16 + fr;
            int sw = (row & 7) << 4;
            bh[nn] = *(const bf8_t*)&ldsB[row * 64 + ((kq ^ sw) >> 1)];
            bl[nn] = *(const bf8_t*)&ldsB[row * 64 + (((kq + 64) ^ sw) >> 1)];
        }
#pragma unroll
        for (int m = 0; m < 4; ++m)
#pragma unroll
            for (int nn = 0; nn < 4; ++nn) {
                acc[m][nn] = __builtin_amdgcn_mfma_f32_16x16x32_bf16(ah[m], bh[nn], acc[m][nn], 0, 0, 0);
                acc[m][nn] = __builtin_amdgcn_mfma_f32_16x16x32_bf16(al[m], bh[nn], acc[m][nn], 0, 0, 0);
                acc[m][nn] = __builtin_amdgcn_mfma_f32_16x16x32_bf16(ah[m], bl[nn], acc[m][nn], 0, 0, 0);
            }
        __syncthreads();
    }

    const int efr = lane & 15, efq = lane >> 4;
#pragma unroll
    for (int m = 0; m < 4; ++m) {
#pragma unroll
        for (int i = 0; i < 4; ++i) {
            long row = brow + wr + m * 16 + efq * 4 + i;
            if (row >= n) continue;
#pragma unroll
            for (int nn = 0; nn < 4; ++nn) {
                int col = (int)bcol + wc + nn * 16 + efr;
                float v = acc[m][nn][i];
                if (bias) v += bias[col];
                if (do_relu) v = fmaxf(v, 0.f);
                if (resid) v += resid[row * M + col];
                if (Cf) Cf[row * M + col] = v;
                if (Cb) Cb[row * M + col] = f2bf(v);
                if (Chl) {
                    unsigned short hb = f2bf(v);
                    float lo = v - bf2f(hb);
                    size_t cb = (row * (size_t)(M >> 5) + (col >> 5)) * 64 + (col & 31);
                    Chl[cb] = hb;
                    Chl[cb + 32] = f2bf(lo);
                }
            }
        }
    }
}

// ---------------------------------------------------------------------------
// Fused Wo+FF: hnew = ac@Wo + bo + h ; h = hnew + relu(hnew@W1+b1)@W2 + b2.
// 64-row tiles, 36 B-tiles (4 Wo + 4c x {4 W1, 4 W2}) through double-buffered
// ldsB (stage t+1 before compute t). hnew kept in regs; its bf16-hi goes to
// swizzled LDS A-buffer for the W1 phases. mid stays in LDS. Arithmetic is
// bit-identical to the unfused Wo-gemm + ff chain.
// LDS 64 KB -> 2 blocks/CU.
// ---------------------------------------------------------------------------
#define FF_STAGE(T, BUF) do {                                                   \
    _Pragma("unroll")                                                           \
    for (int i_ = 0; i_ < 4; ++i_) {                                            \
        int row_ = i_ * 32 + srow;                                              \
        const unsigned short* srcp_;                                            \
        if ((T) < 4) {                                                          \
            srcp_ = WoT + ((size_t)row_ * 4 + (T)) * 64 + kbg;                  \
        } else {                                                                \
            const int tt_ = (T) - 4;                                            \
            const int c_ = tt_ >> 3, ph_ = (tt_ >> 2) & 1, j_ = tt_ & 3;        \
            srcp_ = (ph_ == 0)                                                  \
                ? W1T + (((size_t)c_ * 128 + row_) * 4 + j_) * 64 + kbg         \
                : W2T + ((size_t)row_ * 16 + (c_ * 4 + j_)) * 64 + kbg;         \
        }                                                                       \
        GLD16(srcp_, &ldsB[BUF][((size_t)i_ * 256 + tid) * 8]);                 \
    }                                                                           \
} while (0)

__global__ __launch_bounds__(256, 2) void ffwo_fused(
    const unsigned short* __restrict__ acp,    // [NPAD][128] plain bf16 (attn out)
    const unsigned short* __restrict__ WoT,    // [128][4][2][32]
    const unsigned short* __restrict__ W1T,    // [512][4][2][32]
    const unsigned short* __restrict__ W2T,    // [128][16][2][32]
    const float* __restrict__ bo,              // [128]
    const float* __restrict__ b1,              // [512]
    const float* __restrict__ b2,              // [128]
    float* __restrict__ h,                     // [NPAD][128] resid in / out
    unsigned short* __restrict__ hcout,        // [NPAD][4][2][32] or null
    int n)
{
    __shared__ unsigned short ldsB[2][128 * 64];  // 32 KB double buffer
    __shared__ unsigned short midb[64 * 128];     // 16 KB mid (bf16, swizzled)
    __shared__ unsigned short Ahi[64 * 128];      // 16 KB hi(hnew) (swizzled)

    const int tid = threadIdx.x;
    const int lane = tid & 63;
    const int wid = tid >> 6;
    const int wr = (wid >> 1) * 32;             // {0,32}
    const int wc = (wid & 1) * 64;              // {0,64}
    const long brow = (long)blockIdx.x * 64;

    const int srow = tid >> 3;
    const int kbg = (((tid & 7) << 4) ^ ((srow & 7) << 4)) >> 1;  // B pre-swizzle
    const int fr = lane & 15;
    const int kq = (lane >> 4) << 4;            // k-group byte offset
    const int kq4 = lane >> 4;
    const int efr = lane & 15, efq = lane >> 4;

    // A fragments for the Wo phase (acp plain bf16), loaded once.
    bf8_t ahw[2][4];
#pragma unroll
    for (int m = 0; m < 2; ++m) {
        long arow = brow + wr + m * 16 + fr;
#pragma unroll
        for (int kc = 0; kc < 4; ++kc)
            ahw[m][kc] = *(const bf8_t*)&acp[arow * 128 + kc * 32 + kq4 * 8];
    }

    FF_STAGE(0, 0);

    f4_t accW[2][4];
    f4_t acc1[2][4];
    f4_t acc2[2][4];
    f4_t hnew[2][4];
#pragma unroll
    for (int m = 0; m < 2; ++m)
#pragma unroll
        for (int nn = 0; nn < 4; ++nn) {
            accW[m][nn][0] = 0.f; accW[m][nn][1] = 0.f;
            accW[m][nn][2] = 0.f; accW[m][nn][3] = 0.f;
            acc2[m][nn][0] = 0.f; acc2[m][nn][1] = 0.f;
            acc2[m][nn][2] = 0.f; acc2[m][nn][3] = 0.f;
        }

    __syncthreads();   // buf0 staged

#pragma unroll
    for (int t = 0; t < 36; ++t) {
        const int cur = t & 1;
        if (t < 35) FF_STAGE(t + 1, cur ^ 1);

        if (t < 4) {
            // ---- Wo tile kc=t: accW += ac @ Wo[kc] ----
            bf8_t bh[4], bl[4];
#pragma unroll
            for (int nn = 0; nn < 4; ++nn) {
                int rowb = wc + nn * 16 + fr;
                int sw = (rowb & 7) << 4;
                bh[nn] = *(const bf8_t*)&ldsB[cur][rowb * 64 + ((kq ^ sw) >> 1)];
                bl[nn] = *(const bf8_t*)&ldsB[cur][rowb * 64 + (((kq + 64) ^ sw) >> 1)];
            }
#pragma unroll
            for (int m = 0; m < 2; ++m)
#pragma unroll
                for (int nn = 0; nn < 4; ++nn) {
                    accW[m][nn] = __builtin_amdgcn_mfma_f32_16x16x32_bf16(ahw[m][t], bh[nn], accW[m][nn], 0, 0, 0);
                    accW[m][nn] = __builtin_amdgcn_mfma_f32_16x16x32_bf16(ahw[m][t], bl[nn], accW[m][nn], 0, 0, 0);
                }
            if (t == 3) {
                // hnew = accW + bo + h(resid); hi(hnew) -> Ahi (swizzled)
#pragma unroll
                for (int m = 0; m < 2; ++m)
#pragma unroll
                    for (int i = 0; i < 4; ++i) {
                        int lrow = wr + m * 16 + efq * 4 + i;
                        long row = brow + lrow;
#pragma unroll
                        for (int nn = 0; nn < 4; ++nn) {
                            int col = wc + nn * 16 + efr;
                            float v = accW[m][nn][i] + bo[col] + h[row * 128 + col];
                            hnew[m][nn][i] = v;
                            Ahi[(lrow << 7) + ((((col << 1) ^ ((lrow & 7) << 4))) >> 1)] = f2bf(v);
                        }
                    }
            }
        } else {
            const int tt = t - 4, c = tt >> 3, ph = (tt >> 2) & 1, j = tt & 3;
            if (ph == 0) {
                // ---- W1 tile: acc1 += hi(hnew) @ W1[c][j] ----
                if (j == 0) {
#pragma unroll
                    for (int m = 0; m < 2; ++m)
#pragma unroll
                        for (int nn = 0; nn < 4; ++nn) {
                            acc1[m][nn][0] = 0.f; acc1[m][nn][1] = 0.f;
                            acc1[m][nn][2] = 0.f; acc1[m][nn][3] = 0.f;
                        }
                }
                bf8_t ah[2], bh[4], bl[4];
#pragma unroll
                for (int m = 0; m < 2; ++m) {
                    int lrow = wr + m * 16 + fr;
                    int kbyte = (j * 64 + kq) ^ ((lrow & 7) << 4);
                    ah[m] = *(const bf8_t*)&Ahi[(lrow << 7) + (kbyte >> 1)];
                }
#pragma unroll
                for (int nn = 0; nn < 4; ++nn) {
                    int rowb = wc + nn * 16 + fr;
                    int sw = (rowb & 7) << 4;
                    bh[nn] = *(const bf8_t*)&ldsB[cur][rowb * 64 + ((kq ^ sw) >> 1)];
                    bl[nn] = *(const bf8_t*)&ldsB[cur][rowb * 64 + (((kq + 64) ^ sw) >> 1)];
                }
#pragma unroll
                for (int m = 0; m < 2; ++m)
#pragma unroll
                    for (int nn = 0; nn < 4; ++nn) {
                        acc1[m][nn] = __builtin_amdgcn_mfma_f32_16x16x32_bf16(ah[m], bh[nn], acc1[m][nn], 0, 0, 0);
                        acc1[m][nn] = __builtin_amdgcn_mfma_f32_16x16x32_bf16(ah[m], bl[nn], acc1[m][nn], 0, 0, 0);
                    }
                if (j == 3) {
                    // relu(+b1) -> midb (bf16, byte^((row&7)<<4))
#pragma unroll
                    for (int m = 0; m < 2; ++m)
#pragma unroll
                        for (int i = 0; i < 4; ++i) {
                            int lrow = wr + m * 16 + efq * 4 + i;
#pragma unroll
                            for (int nn = 0; nn < 4; ++nn) {
                                int col = wc + nn * 16 + efr;
                                float v = fmaxf(acc1[m][nn][i] + b1[c * 128 + col], 0.f);
                                int e2 = (lrow << 7) + ((((col << 1) ^ ((lrow & 7) << 4))) >> 1);
                                midb[e2] = f2bf(v);
                            }
                        }
                }
            } else {
                // ---- W2 tile: acc2 += mid @ W2[c*4+j] ----
                bf8_t am[2], bh2[4], bl2[4];
#pragma unroll
                for (int m = 0; m < 2; ++m) {
                    int lrow = wr + m * 16 + fr;
                    int kbyte = (j * 64 + kq) ^ ((lrow & 7) << 4);
                    am[m] = *(const bf8_t*)&midb[(lrow << 7) + (kbyte >> 1)];
                }
#pragma unroll
                for (int nn = 0; nn < 4; ++nn) {
                    int rowb = wc + nn * 16 + fr;
                    int sw = (rowb & 7) << 4;
                    bh2[nn] = *(const bf8_t*)&ldsB[cur][rowb * 64 + ((kq ^ sw) >> 1)];
                    bl2[nn] = *(const bf8_t*)&ldsB[cur][rowb * 64 + (((kq + 64) ^ sw) >> 1)];
                }
#pragma unroll
                for (int m = 0; m < 2; ++m)
#pragma unroll
                    for (int nn = 0; nn < 4; ++nn) {
                        acc2[m][nn] = __builtin_amdgcn_mfma_f32_16x16x32_bf16(am[m], bh2[nn], acc2[m][nn], 0, 0, 0);
                        acc2[m][nn] = __builtin_amdgcn_mfma_f32_16x16x32_bf16(am[m], bl2[nn], acc2[m][nn], 0, 0, 0);
                    }
            }
        }
        __syncthreads();
    }

    // final epilogue: h = hnew + ff + b2 (+ hc hi/lo unless last layer)
#pragma unroll
    for (int m = 0; m < 2; ++m)
#pragma unroll
        for (int i = 0; i < 4; ++i) {
            long row = brow + wr + m * 16 + efq * 4 + i;
            if (row >= n) continue;
#pragma unroll
            for (int nn = 0; nn < 4; ++nn) {
                int col = wc + nn * 16 + efr;
                float v = hnew[m][nn][i] + acc2[m][nn][i] + b2[col];
                h[row * 128 + col] = v;
                if (hcout) {
                    unsigned short hb = f2bf(v);
                    size_t cb = (row * (size_t)4 + (col >> 5)) * 64 + (col & 31);
                    hcout[cb] = hb;
                    hcout[cb + 32] = f2bf(v - bf2f(hb));
                }
            }
        }
}

__global__ void cvt_x_kernel(const float* __restrict__ x, unsigned short* __restrict__ xc)
{
    int idx = blockIdx.x * 256 + threadIdx.x;
    if (idx >= NN * 128) return;
    int node = idx >> 7, col = idx & 127;
    float v = (col < IN_DIM) ? x[(size_t)node * IN_DIM + col] : 0.f;
    unsigned short hb = f2bf(v);
    float lo = v - bf2f(hb);
    size_t b = (size_t)node * 256 + (col >> 5) * 64 + (col & 31);
    xc[b] = hb;
    xc[b + 32] = f2bf(lo);
}

// 16 weight matrices: 1 emb + (Wqk, Wv, Wo, W1, W2) x 3 layers
struct WDesc { const float* W; unsigned short* Wt; int K, nkpad, M, base; };
struct WDescs { WDesc d[16]; int n; int total; };

__global__ void wcvt_all_kernel(WDescs ds)
{
    int idx = blockIdx.x * 256 + threadIdx.x;
    if (idx >= ds.total) return;
    int di = 0;
    while (di + 1 < ds.n && idx >= ds.d[di + 1].base) ++di;
    WDesc w = ds.d[di];
    int loc = idx - w.base;
    int m = loc % w.M;
    int kc = loc / w.M;
    size_t ob = ((size_t)m * w.nkpad + kc) * 64;
    for (int i = 0; i < 32; ++i) {
        int k = kc * 32 + i;
        float v = (k < w.K) ? w.W[(size_t)k * w.M + m] : 0.f;
        unsigned short hb = f2bf(v);
        w.Wt[ob + i] = hb;
        w.Wt[ob + 32 + i] = f2bf(v - bf2f(hb));
    }
}

__global__ void count_kernel(const int* __restrict__ dst, int* __restrict__ counts)
{
    int e = blockIdx.x * 256 + threadIdx.x;
    if (e < EE) atomicAdd(&counts[dst[e]], 1);
}

__global__ __launch_bounds__(1024) void scan1_kernel(
    const int* __restrict__ counts, int* __restrict__ offsets, int* __restrict__ bsums)
{
    __shared__ int buf[1024];
    int tid = threadIdx.x;
    int i = blockIdx.x * 1024 + tid;
    int v = (i < NN) ? counts[i] : 0;
    buf[tid] = v;
    __syncthreads();
    for (int off = 1; off < 1024; off <<= 1) {
        int t = (tid >= off) ? buf[tid - off] : 0;
        __syncthreads();
        buf[tid] += t;
        __syncthreads();
    }
    if (i < NN) offsets[i + 1] = buf[tid];
    if (tid == 1023) bsums[blockIdx.x] = buf[1023];
}

__global__ void scan2_kernel(int* __restrict__ bsums, int nb)
{
    __shared__ int buf[64];
    int tid = threadIdx.x;
    int v = (tid < nb) ? bsums[tid] : 0;
    buf[tid] = v;
    __syncthreads();
    for (int off = 1; off < 64; off <<= 1) {
        int t = (tid >= off) ? buf[tid - off] : 0;
        __syncthreads();
        buf[tid] += t;
        __syncthreads();
    }
    if (tid < nb) bsums[tid] = buf[tid] - v;   // exclusive
}

__global__ __launch_bounds__(1024) void scan3_kernel(
    int* __restrict__ offsets, const int* __restrict__ bsums)
{
    int i = blockIdx.x * 1024 + threadIdx.x;
    if (i < NN) offsets[i + 1] += bsums[blockIdx.x];
    if (i == 0) offsets[0] = 0;
}

__global__ void fill_kernel(const int* __restrict__ src, const int* __restrict__ dst,
                            const int* __restrict__ offsets, int* __restrict__ cursor,
                            int* __restrict__ csr_src)
{
    int e = blockIdx.x * 256 + threadIdx.x;
    if (e < EE) {
        int d = dst[e];
        int pos = atomicAdd(&cursor[d], 1);
        csr_src[offsets[d] + pos] = src[e];
    }
}

// ---------------------------------------------------------------------------
// Fused attention: one wave per dst node; 8 heads x 8 lanes (2 dims/lane).
// QKV plain bf16 [n][384] (q|k|v). Online softmax, 4-edge unrolled.
// Output: plain bf16 ac[n][128].
// ---------------------------------------------------------------------------
__global__ __launch_bounds__(256) void attn_kernel(
    const unsigned short* __restrict__ QKV,
    const int* __restrict__ offsets, const int* __restrict__ csr_src,
    unsigned short* __restrict__ ac)    // [n][128] plain bf16
{
    int wave = threadIdx.x >> 6;
    int lane = threadIdx.x & 63;
    int node = blockIdx.x * 4 + wave;
    if (node >= NN) return;
    int qoff = ((lane >> 3) << 4) + ((lane & 7) << 1);
    ushort2 k2 = *(const ushort2*)&QKV[(size_t)node * 384 + 128 + qoff];
    float kx = bf2f(k2.x), ky = bf2f(k2.y);
    float m = -INFINITY, s = 0.f, a0 = 0.f, a1 = 0.f;
    int e = offsets[node], end = offsets[node + 1];
    for (; e + 3 < end; e += 4) {
        int j0 = csr_src[e], j1 = csr_src[e + 1], j2 = csr_src[e + 2], j3 = csr_src[e + 3];
        ushort2 q0 = *(const ushort2*)&QKV[(size_t)j0 * 384 + qoff];
        ushort2 q1 = *(const ushort2*)&QKV[(size_t)j1 * 384 + qoff];
        ushort2 q2 = *(const ushort2*)&QKV[(size_t)j2 * 384 + qoff];
        ushort2 q3 = *(const ushort2*)&QKV[(size_t)j3 * 384 + qoff];
        ushort2 v0 = *(const ushort2*)&QKV[(size_t)j0 * 384 + 256 + qoff];
        ushort2 v1 = *(const ushort2*)&QKV[(size_t)j1 * 384 + 256 + qoff];
        ushort2 v2 = *(const ushort2*)&QKV[(size_t)j2 * 384 + 256 + qoff];
        ushort2 v3 = *(const ushort2*)&QKV[(size_t)j3 * 384 + 256 + qoff];
        float p0 = kx * bf2f(q0.x) + ky * bf2f(q0.y);
        float p1 = kx * bf2f(q1.x) + ky * bf2f(q1.y);
        float p2 = kx * bf2f(q2.x) + ky * bf2f(q2.y);
        float p3 = kx * bf2f(q3.x) + ky * bf2f(q3.y);
        p0 += __shfl_xor(p0, 1, 64); p0 += __shfl_xor(p0, 2, 64); p0 += __shfl_xor(p0, 4, 64);
        p1 += __shfl_xor(p1, 1, 64); p1 += __shfl_xor(p1, 2, 64); p1 += __shfl_xor(p1, 4, 64);
        p2 += __shfl_xor(p2, 1, 64); p2 += __shfl_xor(p2, 2, 64); p2 += __shfl_xor(p2, 4, 64);
        p3 += __shfl_xor(p3, 1, 64); p3 += __shfl_xor(p3, 2, 64); p3 += __shfl_xor(p3, 4, 64);
        float sc0 = p0 * 0.25f, sc1 = p1 * 0.25f, sc2 = p2 * 0.25f, sc3 = p3 * 0.25f;
        float mx = fmaxf(fmaxf(fmaxf(sc0, sc1), fmaxf(sc2, sc3)), m);
        float corr = __expf(m - mx);
        float w0 = __expf(sc0 - mx), w1 = __expf(sc1 - mx);
        float w2 = __expf(sc2 - mx), w3 = __expf(sc3 - mx);
        s  = s  * corr + (w0 + w1) + (w2 + w3);
        a0 = a0 * corr + w0 * bf2f(v0.x) + w1 * bf2f(v1.x) + w2 * bf2f(v2.x) + w3 * bf2f(v3.x);
        a1 = a1 * corr + w0 * bf2f(v0.y) + w1 * bf2f(v1.y) + w2 * bf2f(v2.y) + w3 * bf2f(v3.y);
        m = mx;
    }
    if (e + 1 < end) {
        int j0 = csr_src[e], j1 = csr_src[e + 1];
        ushort2 q0 = *(const ushort2*)&QKV[(size_t)j0 * 384 + qoff];
        ushort2 v0 = *(const ushort2*)&QKV[(size_t)j0 * 384 + 256 + qoff];
        ushort2 q1 = *(const ushort2*)&QKV[(size_t)j1 * 384 + qoff];
        ushort2 v1 = *(const ushort2*)&QKV[(size_t)j1 * 384 + 256 + qoff];
        float p0 = kx * bf2f(q0.x) + ky * bf2f(q0.y);
        float p1 = kx * bf2f(q1.x) + ky * bf2f(q1.y);
        p0 += __shfl_xor(p0, 1, 64); p0 += __shfl_xor(p0, 2, 64); p0 += __shfl_xor(p0, 4, 64);
        p1 += __shfl_xor(p1, 1, 64); p1 += __shfl_xor(p1, 2, 64); p1 += __shfl_xor(p1, 4, 64);
        float sc0 = p0 * 0.25f, sc1 = p1 * 0.25f;
        float mn = fmaxf(m, fmaxf(sc0, sc1));
        float corr = __expf(m - mn);
        float w0 = __expf(sc0 - mn), w1 = __expf(sc1 - mn);
        s  = s  * corr + w0 + w1;
        a0 = a0 * corr + w0 * bf2f(v0.x) + w1 * bf2f(v1.x);
        a1 = a1 * corr + w0 * bf2f(v0.y) + w1 * bf2f(v1.y);
        m = mn;
        e += 2;
    }
    if (e < end) {
        int j = csr_src[e];
        ushort2 qj = *(const ushort2*)&QKV[(size_t)j * 384 + qoff];
        ushort2 vj = *(const ushort2*)&QKV[(size_t)j * 384 + 256 + qoff];
        float p = kx * bf2f(qj.x) + ky * bf2f(qj.y);
        p += __shfl_xor(p, 1, 64); p += __shfl_xor(p, 2, 64); p += __shfl_xor(p, 4, 64);
        float score = p * 0.25f;
        float mn = fmaxf(m, score);
        float corr = __expf(m - mn);
        float w = __expf(score - mn);
        s  = s  * corr + w;
        a0 = a0 * corr + w * bf2f(vj.x);
        a1 = a1 * corr + w * bf2f(vj.y);
        m = mn;
    }
    float inv = 1.f / (s + 1e-16f);
    ushort2 o;
    o.x = f2bf(a0 * inv);
    o.y = f2bf(a1 * inv);
    *(ushort2*)&ac[(size_t)node * 128 + qoff] = o;
}

// ---------------------------------------------------------------------------
// Mean pool per graph: 256 rows/block striped 8 ways, float4 cols
// ---------------------------------------------------------------------------
__global__ __launch_bounds__(256) void pool_kernel(
    const float* __restrict__ h, const int* __restrict__ batch,
    float* __restrict__ sums, int* __restrict__ cnts)
{
    int tid = threadIdx.x;
    int c4 = tid & 31;
    int rs = tid >> 5;
    int start = blockIdx.x * 256;
    int r0 = start + rs;
    if (r0 >= NN) return;
    int lim = min(start + 256, NN);
    float4 acc = make_float4(0.f, 0.f, 0.f, 0.f);
    int cnt = 0;
    int cur = batch[r0];
    for (int r = r0; r < lim; r += 8) {
        int g = batch[r];
        if (g != cur) {
            atomicAdd(&sums[cur * DD + c4 * 4 + 0], acc.x);
            atomicAdd(&sums[cur * DD + c4 * 4 + 1], acc.y);
            atomicAdd(&sums[cur * DD + c4 * 4 + 2], acc.z);
            atomicAdd(&sums[cur * DD + c4 * 4 + 3], acc.w);
            if (c4 == 0) atomicAdd(&cnts[cur], cnt);
            acc = make_float4(0.f, 0.f, 0.f, 0.f);
            cnt = 0; cur = g;
        }
        float4 v = *(const float4*)&h[(size_t)r * DD + c4 * 4];
        acc.x += v.x; acc.y += v.y; acc.z += v.z; acc.w += v.w;
        ++cnt;
    }
    atomicAdd(&sums[cur * DD + c4 * 4 + 0], acc.x);
    atomicAdd(&sums[cur * DD + c4 * 4 + 1], acc.y);
    atomicAdd(&sums[cur * DD + c4 * 4 + 2], acc.z);
    atomicAdd(&sums[cur * DD + c4 * 4 + 3], acc.w);
    if (c4 == 0) atomicAdd(&cnts[cur], cnt);
}

__global__ void finalize_kernel(const float* __restrict__ sums, const int* __restrict__ cnts,
                                float* __restrict__ out)
{
    int g = blockIdx.x, c = threadIdx.x;
    out[g * DD + c] = sums[g * DD + c] / fmaxf((float)cnts[g], 1.f);
}

extern "C" void kernel_launch(void* const* d_in, const int* in_sizes, int n_in,
                              void* d_out, int out_size, void* d_ws, size_t ws_size,
                              hipStream_t stream)
{
    const float* x     = (const float*)d_in[0];
    const float* emb_W = (const float*)d_in[1];
    const float* Wqk   = (const float*)d_in[2];
    const float* Wv    = (const float*)d_in[3];
    const float* Wo    = (const float*)d_in[4];
    const float* bo    = (const float*)d_in[5];
    const float* W1    = (const float*)d_in[6];
    const float* b1    = (const float*)d_in[7];
    const float* W2    = (const float*)d_in[8];
    const float* b2    = (const float*)d_in[9];
    const int* eidx    = (const int*)d_in[10];
    const int* batch   = (const int*)d_in[11];
    float* out = (float*)d_out;

    char* base = (char*)d_ws;
    size_t off = 0;
    auto alloc = [&](size_t bytes) { char* p = base + off; off = (off + bytes + 255) & ~(size_t)255; return p; };

    float*          h    = (float*)alloc((size_t)NPAD * DD * 4);
    unsigned short* hc   = (unsigned short*)alloc((size_t)NPAD * 2 * DD * 2);
    char*           regB = alloc((size_t)NPAD * 384 * 2 + (size_t)NPAD * 128 * 2 + 256);
    unsigned short* xc   = (unsigned short*)regB;                                // phase 0
    unsigned short* QKVb = (unsigned short*)regB;                                // per-layer ph 1
    unsigned short* acp  = (unsigned short*)(regB + (size_t)NPAD * 384 * 2);     // [NPAD][128] plain

    unsigned short* WqkvT = (unsigned short*)alloc((size_t)LL * 384 * 256 * 2);
    unsigned short* WoT   = (unsigned short*)alloc((size_t)LL * 128 * 256 * 2);
    unsigned short* W1T   = (unsigned short*)alloc((size_t)LL * 512 * 256 * 2);
    unsigned short* W2T   = (unsigned short*)alloc((size_t)LL * 128 * 1024 * 2);
    unsigned short* embT  = (unsigned short*)alloc((size_t)128 * 256 * 2);

    int* counts  = (int*)alloc((NN + 1) * 4);
    int* offsets = (int*)alloc((NN + 1) * 4);
    int* cursor  = (int*)alloc(NN * 4);
    int* bsums   = (int*)alloc(64 * 4);
    int* csr_src = (int*)alloc((size_t)EE * 4);
    float* sums  = (float*)alloc(GG * DD * 4 + GG * 4);
    int* cnts    = (int*)(sums + GG * DD);

    const int* src = eidx;
    const int* dst = eidx + EE;

    hipMemsetAsync(counts, 0, (NN + 1) * sizeof(int), stream);
    hipMemsetAsync(cursor, 0, NN * sizeof(int), stream);
    hipMemsetAsync(sums, 0, GG * DD * sizeof(float) + GG * sizeof(int), stream);

    const int NB1 = (NN + 1023) / 1024;   // 49
    count_kernel<<<dim3((EE + 255) / 256), dim3(256), 0, stream>>>(dst, counts);
    scan1_kernel<<<dim3(NB1), dim3(1024), 0, stream>>>(counts, offsets, bsums);
    scan2_kernel<<<dim3(1), dim3(64), 0, stream>>>(bsums, NB1);
    scan3_kernel<<<dim3(NB1), dim3(1024), 0, stream>>>(offsets, bsums);
    fill_kernel<<<dim3((EE + 255) / 256), dim3(256), 0, stream>>>(src, dst, offsets, cursor, csr_src);

    WDescs ds;
    int b = 0, di = 0;
    auto addw = [&](const float* W, unsigned short* Wt, int K, int nkpad, int M) {
        ds.d[di].W = W; ds.d[di].Wt = Wt; ds.d[di].K = K;
        ds.d[di].nkpad = nkpad; ds.d[di].M = M; ds.d[di].base = b;
        b += M * nkpad; ++di;
    };
    addw(emb_W, embT, IN_DIM, 4, DD);
    for (int l = 0; l < LL; ++l) {
        addw(Wqk + (size_t)l * DD * 256, WqkvT + (size_t)l * 384 * 256, DD, 4, 256);
        addw(Wv  + (size_t)l * DD * DD,  WqkvT + (size_t)l * 384 * 256 + 256 * 256, DD, 4, 128);
        addw(Wo  + (size_t)l * DD * DD,  WoT + (size_t)l * 128 * 256, DD, 4, 128);
        addw(W1  + (size_t)l * DD * FFD, W1T + (size_t)l * 512 * 256, DD, 4, 512);
        addw(W2  + (size_t)l * FFD * DD, W2T + (size_t)l * 128 * 1024, FFD, 16, 128);
    }
    ds.n = di; ds.total = b;   // di == 16
    wcvt_all_kernel<<<dim3((b + 255) / 256), dim3(256), 0, stream>>>(ds);

    cvt_x_kernel<<<dim3((NN * 128 + 255) / 256), dim3(256), 0, stream>>>(x, xc);

    dim3 blk(256);
    const int gx = (NN + 127) / 128;   // 391
    const int gx2 = (NN + 63) / 64;    // 782

    // emb: h = x @ emb_W  (fp32 h + hi/lo hc)
    mfma_gemm<<<dim3(gx, 1), blk, 0, stream>>>(
        xc, embT, nullptr, nullptr, h, hc, nullptr, NN, 4, DD, 0);

    for (int l = 0; l < LL; ++l) {
        // QKV = h @ [Wqk|Wv] -> plain bf16 [n][384]
        mfma_gemm<<<dim3(gx, 3), blk, 0, stream>>>(
            hc, WqkvT + (size_t)l * 384 * 256, nullptr, nullptr,
            nullptr, nullptr, QKVb, NN, 4, 384, 0);
        attn_kernel<<<dim3(NN / 4), blk, 0, stream>>>(QKVb, offsets, csr_src, acp);
        // h = (h + ac@Wo + bo) + relu(...)@W2 + b2 : fully fused
        ffwo_fused<<<dim3(gx2), blk, 0, stream>>>(
            acp, WoT + (size_t)l * 128 * 256,
            W1T + (size_t)l * 512 * 256, W2T + (size_t)l * 128 * 1024,
            bo + (size_t)l * DD, b1 + (size_t)l * FFD, b2 + (size_t)l * DD, h,
            (l == LL - 1) ? nullptr : hc, NN);
    }

    pool_kernel<<<dim3((NN + 255) / 256), blk, 0, stream>>>(h, batch, sums, cnts);
    finalize_kernel<<<dim3(GG), dim3(128), 0, stream>>>(sums, cnts, out);
}